// Round 1
// baseline (141.646 us; speedup 1.0000x reference)
//
#include <hip/hip_runtime.h>
#include <math.h>

// Problem constants (K=4, R=16384, kappa=32, NX=3, NF=13, DOUT=64, n=16)
#define KR    65536   // K*R points
#define RPTS  16384   // R (power of 2 -> shifts)
#define DOUTC 64
#define KAPPA 32

// ---------------------------------------------------------------------------
// Kernel 1: Q[point][d] = dot(P[point], H[d]),  P = [X | F] (3 + 13 = 16)
// One wave per point (lane = d), grid-stride. H row cached in 16 VGPRs.
// Writes are perfectly coalesced (lane d -> Q[point*64+d]).
// ---------------------------------------------------------------------------
__global__ __launch_bounds__(256) void q_kernel(
    const float* __restrict__ X, const float* __restrict__ F,
    const float* __restrict__ H, float* __restrict__ Q) {
  const int lane = threadIdx.x & 63;
  const int wave = threadIdx.x >> 6;
  const int wid = blockIdx.x * 4 + wave;
  const int nwaves = gridDim.x * 4;
  // H is [64][16] row-major; lane d loads its row (64B-aligned -> 4x float4)
  const float4 h0 = *(const float4*)(H + lane * 16 + 0);
  const float4 h1 = *(const float4*)(H + lane * 16 + 4);
  const float4 h2 = *(const float4*)(H + lane * 16 + 8);
  const float4 h3 = *(const float4*)(H + lane * 16 + 12);
  for (int point = wid; point < KR; point += nwaves) {
    const float* xp = X + point * 3;   // wave-uniform -> broadcast loads
    const float* fp = F + point * 13;
    float q = xp[0] * h0.x + xp[1] * h0.y + xp[2] * h0.z
            + fp[0] * h0.w
            + fp[1] * h1.x + fp[2] * h1.y + fp[3] * h1.z + fp[4] * h1.w
            + fp[5] * h2.x + fp[6] * h2.y + fp[7] * h2.z + fp[8] * h2.w
            + fp[9] * h3.x + fp[10] * h3.y + fp[11] * h3.z + fp[12] * h3.w;
    Q[point * 64 + lane] = q;
  }
}

// ---------------------------------------------------------------------------
// Kernel 2: per point r: m[d] = relu(max_i Q[k, N[k,r,i], d]);
//           Y[r][e] = relu(sum_d m[d]*gamma[d][e] + bias[e])
// Block = 256 threads (4 waves), 64 points per block, 1024 blocks.
// Phase A: wave w max-gathers 16 points (lane = d, 256B coalesced reads from
//          L2-resident Q), writes M_lds[p][d] (row stride 68 to break banks).
// Phase B: 16x16 thread grid, 4x4 register tile each, classic LDS GEMM
//          M(64x64) @ gamma(64x64). a-reads are 16-lane broadcasts; b-reads
//          are float4, 2-way bank aliasing only (free).
// ---------------------------------------------------------------------------
__global__ __launch_bounds__(256) void gather_gemm_kernel(
    const float* __restrict__ Q, const int* __restrict__ N,
    const float* __restrict__ gamma, const float* __restrict__ gbias,
    float* __restrict__ Y) {
  __shared__ float Gl[64 * 64];   // gamma[d][e]
  __shared__ float Ml[64 * 68];   // M[p][d], padded stride
  __shared__ float Bl[64];

  const int t = threadIdx.x;
  // stage gamma (4096 floats) as float4: 1024 float4 / 256 threads = 4 each
  {
    const float4* gsrc = (const float4*)gamma;
    float4* gdst = (float4*)Gl;
    #pragma unroll
    for (int i = 0; i < 4; ++i) gdst[t + 256 * i] = gsrc[t + 256 * i];
    if (t < 64) Bl[t] = gbias[t];
  }

  const int lane = t & 63;
  const int wave = t >> 6;
  const int base = blockIdx.x * 64;   // first point of this block

  // ---- Phase A: max-gather 16 points per wave ----
  for (int p = 0; p < 16; ++p) {
    const int point = base + wave * 16 + p;
    const int k = point >> 14;                    // / R
    const float* Qk = Q + ((size_t)k << 20);      // k*R*64
    const int* np = N + point * KAPPA;
    float m = -INFINITY;
    #pragma unroll
    for (int i = 0; i < KAPPA; ++i) {
      const int idx = np[i];
      m = fmaxf(m, Qk[idx * 64 + lane]);
    }
    m = fmaxf(m, 0.0f);                           // relu(max) == max(relu)
    Ml[(wave * 16 + p) * 68 + lane] = m;
  }
  __syncthreads();

  // ---- Phase B: out(64x64) = Ml(64x64) @ Gl(64x64), 4x4 per thread ----
  const int ty = t >> 4;   // 0..15 -> point rows ty*4..ty*4+3
  const int tx = t & 15;   // 0..15 -> out cols  tx*4..tx*4+3
  float acc[4][4] = {};
  #pragma unroll 4
  for (int d = 0; d < 64; ++d) {
    const float a0 = Ml[(ty * 4 + 0) * 68 + d];
    const float a1 = Ml[(ty * 4 + 1) * 68 + d];
    const float a2 = Ml[(ty * 4 + 2) * 68 + d];
    const float a3 = Ml[(ty * 4 + 3) * 68 + d];
    const float4 b = *(const float4*)(Gl + d * 64 + tx * 4);
    acc[0][0] += a0 * b.x; acc[0][1] += a0 * b.y; acc[0][2] += a0 * b.z; acc[0][3] += a0 * b.w;
    acc[1][0] += a1 * b.x; acc[1][1] += a1 * b.y; acc[1][2] += a1 * b.z; acc[1][3] += a1 * b.w;
    acc[2][0] += a2 * b.x; acc[2][1] += a2 * b.y; acc[2][2] += a2 * b.z; acc[2][3] += a2 * b.w;
    acc[3][0] += a3 * b.x; acc[3][1] += a3 * b.y; acc[3][2] += a3 * b.z; acc[3][3] += a3 * b.w;
  }

  // epilogue: add bias, relu, coalesced float4 stores
  const float4 bb = *(const float4*)(Bl + tx * 4);
  #pragma unroll
  for (int i = 0; i < 4; ++i) {
    float4 o;
    o.x = fmaxf(acc[i][0] + bb.x, 0.0f);
    o.y = fmaxf(acc[i][1] + bb.y, 0.0f);
    o.z = fmaxf(acc[i][2] + bb.z, 0.0f);
    o.w = fmaxf(acc[i][3] + bb.w, 0.0f);
    *(float4*)(Y + (size_t)(base + ty * 4 + i) * 64 + tx * 4) = o;
  }
}

extern "C" void kernel_launch(void* const* d_in, const int* in_sizes, int n_in,
                              void* d_out, int out_size, void* d_ws, size_t ws_size,
                              hipStream_t stream) {
  const float* X  = (const float*)d_in[0];
  const float* F  = (const float*)d_in[1];
  const int*   N  = (const int*)d_in[2];
  const float* H  = (const float*)d_in[3];
  const float* G  = (const float*)d_in[4];
  const float* Gb = (const float*)d_in[5];
  float* Y = (float*)d_out;
  float* Q = (float*)d_ws;   // needs KR*64*4 = 16 MiB of scratch

  q_kernel<<<1024, 256, 0, stream>>>(X, F, H, Q);
  gather_gemm_kernel<<<1024, 256, 0, stream>>>(Q, N, G, Gb, Y);
}